// Round 16
// baseline (359.513 us; speedup 1.0000x reference)
//
#include <hip/hip_runtime.h>
#include <hip/hip_bf16.h>
#include <stdint.h>

typedef __attribute__((ext_vector_type(8))) short s8v;   // 8 bf16 = K32 MFMA A/B frag
typedef __attribute__((ext_vector_type(4))) float f4v;   // MFMA C/D frag

#define NE   128
#define NT   2048
#define DIN  128
#define DH   512
#define DOUT 128

#define MFMA32(a,b,c) __builtin_amdgcn_mfma_f32_16x16x32_bf16(a,b,c,0,0,0)

#define LGKM0() asm volatile("s_waitcnt lgkmcnt(0)" ::: "memory")
// raw barrier (no implicit vmcnt drain — gather loads stay in flight across it)
#define BAR() do { asm volatile("" ::: "memory"); \
                   __builtin_amdgcn_s_barrier();  \
                   asm volatile("" ::: "memory"); } while (0)

__device__ __forceinline__ __hip_bfloat162 pk2(float a, float b) {
  float2 t; t.x = a; t.y = b;
  return __float22bfloat162_rn(t);
}

__device__ __forceinline__ s8v pack8(float4 a, float4 b) {
  union { s8v v; __hip_bfloat162 h[4]; } u;
  u.h[0] = pk2(a.x, a.y); u.h[1] = pk2(a.z, a.w);
  u.h[2] = pk2(b.x, b.y); u.h[3] = pk2(b.z, b.w);
  return u.v;
}

// gelu(x) = x * sigmoid(x*(1.5957691 + 0.07135481*x^2))  (tanh-form rewritten)
__device__ __forceinline__ float gelu_f(float x) {
  float x2 = x * x;
  float p  = __builtin_fmaf(x2, 0.07135481f, 1.5957691f);
  float e  = __expf(-x * p);
  return x * __builtin_amdgcn_rcpf(1.0f + e);
}

__device__ __forceinline__ float4 gelu4(f4v v) {
  float4 r;
  r.x = gelu_f(v[0]); r.y = gelu_f(v[1]);
  r.z = gelu_f(v[2]); r.w = gelu_f(v[3]);
  return r;
}

// ---------------- fully fused kernel (r16) ----------------
// r15 evidence: total-moe-pack ~= 175-185us FIXED across 3 different pack
// implementations (r3/r4/r15) => the gap is harness/launch overhead, pack
// was always ~25us. This round removes the pack kernel entirely: each block
// converts its own weight chunks in-kernel (gather fp32 -> cvt -> ds_write,
// same LDS layout as r11, compute section verbatim). Removes: 1 launch,
// ~25us pack wall, 67MB packed-weight HBM round trip. With one kernel,
// total - moe measures the harness overhead exactly.
//
// Per chunk c (32 h-values):
//   LDS W1s slots 0..7: slot = hl*4+ks, value j = W1[ks*32+8q+j][(2c+hl)*16+l16]
//   LDS W2s slots 0..7: slot = ot,      value j = W2[32c+sig_q(j)][ot*16+l16]
//     sig_q(j) = (j<4) ? 4q+j : 16+4q+(j-4)  — bijective, applied to BOTH
//     operands (A-frag is gelu-output order), contraction exact (r9/r11/r15
//     verified, absmax 0.015625 every round).
// Wave wid gathers slots {wid, wid+4} of each (16+16 fp32 scalar loads,
// 4x64B coalesced per j across the wave), cvt+ds_write = 4x ds_write_b128.
// Pipeline per iter c: COMPUTE(c from buf) | cvtwrite(c+1 -> buf^1) |
// gather(c+2, stays in flight across BAR) | lgkmcnt(0); BAR.
// WAR: buf^1 last read at iter c-1, separated by that iter's BAR. RAW:
// lgkm drain + BAR before iter c+1 reads buf^1.
//
// Regs: ga/gb 32 + xf 32 + oacc 64(AGPR) + bases/transients ~40 => ~166 of
// the 168-cap at (256,3). Tripwire: WRITE_SIZE >> 131MB = spill -> revert.
__global__ __launch_bounds__(256, 3) void moe_fused(
    const float* __restrict__ X, const float* __restrict__ W1,
    const float* __restrict__ W2, float* __restrict__ Out) {
  __shared__ __align__(16) ushort W1s[2][4096];  // chunk: 8 slots x 512
  __shared__ __align__(16) ushort W2s[2][4096];  // chunk: 8 ot x 512

  const int tid  = threadIdx.x;
  const int lane = tid & 63;
  const int wid  = tid >> 6;
  const int q    = lane >> 4;
  const int l16  = lane & 15;

  // XCD swizzle: grid 2048 = 8 XCDs x 256 blocks (round-robin assumption).
  const int bid  = blockIdx.x;
  const int wk   = ((bid & 7) << 8) | (bid >> 3);
  const int e    = wk >> 4;
  const int tile = wk & 15;

  const float* Xe = X + ((size_t)e * NT + (size_t)tile * 128) * DIN;
  float* Oe = Out + ((size_t)e * NT + (size_t)tile * 128) * DOUT;

  // gather base pointers (advance one chunk per gather() call)
  // W1: d-row = wid*32 + 8q + j, h = c*32 + hl*16 + l16
  const float* w1p = W1 + (size_t)e * (DIN * DH)
                   + (size_t)(wid * 32 + 8 * q) * DH + l16;
  // W2: h-row = 32c + sig_q(j) = 32c + 4q + rowoff(j), o = ot*16 + l16
  const float* w2p = W2 + (size_t)e * (DH * DOUT)
                   + (size_t)(4 * q) * DOUT + wid * 16 + l16;

  float ga[16], gb[16];   // chunk-(c+1) raw values, live across compute
  auto gather = [&]() {
#pragma unroll
    for (int j = 0; j < 8; ++j) {
      ga[j]     = w1p[(size_t)j * DH];        // slot wid   (hl=0)
      ga[8 + j] = w1p[(size_t)j * DH + 16];   // slot wid+4 (hl=1)
    }
#pragma unroll
    for (int j = 0; j < 8; ++j) {
      const int row = (j < 4) ? j : (12 + j); // j<4: j ; j>=4: 16+(j-4)
      gb[j]     = w2p[(size_t)row * DOUT];        // ot = wid
      gb[8 + j] = w2p[(size_t)row * DOUT + 64];   // ot = wid+4
    }
    w1p += 32;
    w2p += (size_t)32 * DOUT;
  };

  auto cvtwrite = [&](int b) {
    float4 a0 = make_float4(ga[0],  ga[1],  ga[2],  ga[3]);
    float4 a1 = make_float4(ga[4],  ga[5],  ga[6],  ga[7]);
    float4 a2 = make_float4(ga[8],  ga[9],  ga[10], ga[11]);
    float4 a3 = make_float4(ga[12], ga[13], ga[14], ga[15]);
    *(s8v*)&W1s[b][(size_t)wid * 512 + lane * 8]       = pack8(a0, a1);
    *(s8v*)&W1s[b][(size_t)(4 + wid) * 512 + lane * 8] = pack8(a2, a3);
    float4 b0 = make_float4(gb[0],  gb[1],  gb[2],  gb[3]);
    float4 b1 = make_float4(gb[4],  gb[5],  gb[6],  gb[7]);
    float4 b2 = make_float4(gb[8],  gb[9],  gb[10], gb[11]);
    float4 b3 = make_float4(gb[12], gb[13], gb[14], gb[15]);
    *(s8v*)&W2s[b][(size_t)wid * 512 + lane * 8]       = pack8(b0, b1);
    *(s8v*)&W2s[b][(size_t)(4 + wid) * 512 + lane * 8] = pack8(b2, b3);
  };

  // ---- load this wave's X fragments into registers (once) ----
  s8v xf[2][4];
#pragma unroll
  for (int mt = 0; mt < 2; ++mt) {
#pragma unroll
    for (int ks = 0; ks < 4; ++ks) {
      const float* p = Xe + (size_t)(wid * 32 + mt * 16 + l16) * DIN + ks * 32 + q * 8;
      float4 v0 = *(const float4*)p;
      float4 v1 = *(const float4*)(p + 4);
      xf[mt][ks] = pack8(v0, v1);
    }
  }

  const f4v zero4 = {0.0f, 0.0f, 0.0f, 0.0f};
  f4v oacc[2][8];
#pragma unroll
  for (int mt = 0; mt < 2; ++mt)
#pragma unroll
    for (int ot = 0; ot < 8; ++ot) oacc[mt][ot] = zero4;

  // ---- prologue: chunk 0 packed into buf 0; chunk-1 gathers in flight ----
  gather();        // chunk 0 -> ga/gb (compiler inserts the vmcnt wait at use)
  cvtwrite(0);
  gather();        // chunk 1 (stays in flight through the barrier)
  LGKM0(); BAR();

  for (int c = 0; c < 16; ++c) {
    const int buf = c & 1;

    // ---- stage 1, hl=0: K=32 over d (r11 verbatim) ----
    f4v h0[2]; h0[0] = zero4; h0[1] = zero4;
#pragma unroll
    for (int kp = 0; kp < 2; ++kp) {
      s8v af0 = *(const s8v*)&W1s[buf][(kp * 2 + 0) * 512 + lane * 8];
      s8v af1 = *(const s8v*)&W1s[buf][(kp * 2 + 1) * 512 + lane * 8];
      __builtin_amdgcn_s_setprio(1);
      h0[0] = MFMA32(af0, xf[0][kp * 2 + 0], h0[0]);
      h0[1] = MFMA32(af0, xf[1][kp * 2 + 0], h0[1]);
      h0[0] = MFMA32(af1, xf[0][kp * 2 + 1], h0[0]);
      h0[1] = MFMA32(af1, xf[1][kp * 2 + 1], h0[1]);
      __builtin_amdgcn_s_setprio(0);
    }
    float4 ga0 = gelu4(h0[0]);
    float4 ga1 = gelu4(h0[1]);

    // ---- stage 1, hl=1 ----
    f4v h1[2]; h1[0] = zero4; h1[1] = zero4;
#pragma unroll
    for (int kp = 0; kp < 2; ++kp) {
      s8v af0 = *(const s8v*)&W1s[buf][(4 + kp * 2 + 0) * 512 + lane * 8];
      s8v af1 = *(const s8v*)&W1s[buf][(4 + kp * 2 + 1) * 512 + lane * 8];
      __builtin_amdgcn_s_setprio(1);
      h1[0] = MFMA32(af0, xf[0][kp * 2 + 0], h1[0]);
      h1[1] = MFMA32(af0, xf[1][kp * 2 + 0], h1[1]);
      h1[0] = MFMA32(af1, xf[0][kp * 2 + 1], h1[0]);
      h1[1] = MFMA32(af1, xf[1][kp * 2 + 1], h1[1]);
      __builtin_amdgcn_s_setprio(0);
    }

    // ---- pack: a8 position 8q+j -> j<4: hl0 (h=4q+j), j>=4: hl1 (16+4q+j-4)
    s8v a8_0 = pack8(ga0, gelu4(h1[0]));
    s8v a8_1 = pack8(ga1, gelu4(h1[1]));

    // ---- stage 2: K=32, 8 o-tiles, sigma-packed W2 frags ----
#pragma unroll
    for (int op = 0; op < 4; ++op) {
      s8v b0 = *(const s8v*)&W2s[buf][(op * 2 + 0) * 512 + lane * 8];
      s8v b1 = *(const s8v*)&W2s[buf][(op * 2 + 1) * 512 + lane * 8];
      __builtin_amdgcn_s_setprio(1);
      oacc[0][op * 2 + 0] = MFMA32(a8_0, b0, oacc[0][op * 2 + 0]);
      oacc[1][op * 2 + 0] = MFMA32(a8_1, b0, oacc[1][op * 2 + 0]);
      oacc[0][op * 2 + 1] = MFMA32(a8_0, b1, oacc[0][op * 2 + 1]);
      oacc[1][op * 2 + 1] = MFMA32(a8_1, b1, oacc[1][op * 2 + 1]);
      __builtin_amdgcn_s_setprio(0);
    }

    // ---- in-kernel pack of chunk c+1 into the other buffer ----
    if (c < 15) cvtwrite(buf ^ 1);   // consumes ga/gb (chunk c+1)
    if (c < 14) gather();            // issue chunk c+2 (in flight across BAR)
    if (c < 15) { LGKM0(); BAR(); }  // ds_writes visible; WAR via prev BAR
  }

  // ---- epilogue: D layout col=o=l16, row m = 4q + r (C/D map is K-indep) ----
#pragma unroll
  for (int mt = 0; mt < 2; ++mt) {
    const int mb = wid * 32 + mt * 16 + 4 * q;
#pragma unroll
    for (int ot = 0; ot < 8; ++ot) {
      float* p = Oe + (size_t)mb * DOUT + ot * 16 + l16;
      p[0 * DOUT] = oacc[mt][ot][0];
      p[1 * DOUT] = oacc[mt][ot][1];
      p[2 * DOUT] = oacc[mt][ot][2];
      p[3 * DOUT] = oacc[mt][ot][3];
    }
  }
}

extern "C" void kernel_launch(void* const* d_in, const int* in_sizes, int n_in,
                              void* d_out, int out_size, void* d_ws, size_t ws_size,
                              hipStream_t stream) {
  const float* X  = (const float*)d_in[0];
  const float* W1 = (const float*)d_in[1];
  const float* W2 = (const float*)d_in[2];
  float* Out = (float*)d_out;
  (void)d_ws; (void)ws_size;   // no workspace needed — pack fused into moe

  moe_fused<<<NE * (NT / 128), 256, 0, stream>>>(X, W1, W2, Out);
}